// Round 1
// baseline (2327.210 us; speedup 1.0000x reference)
//
#include <hip/hip_runtime.h>
#include <math.h>

#define NSAMP 16384
#define MT 8

// output section offsets (in floats) within d_out:
//   out        (16384,18)   @ 0
//   J_tot      (16384,9,7)  @ 16384*18
//   out_angles (16384,6)    @ 16384*(18+63)
//   J_tot_ang  (16384,6,7)  @ 16384*(18+63+6)
#define OUT0_OFF 0
#define JTOT_OFF (NSAMP*18)
#define OUTA_OFF (NSAMP*(18+63))
#define JANG_OFF (NSAMP*(18+63+6))

__device__ __forceinline__ float sig(float z) { return 1.0f / (1.0f + __expf(-z)); }

// ---------------- pos net: 7 -> 512 -> 512 -> 3 ----------------
__global__ __launch_bounds__(512, 2)
void pos_kernel(const float* __restrict__ x,
                const float* __restrict__ W0, const float* __restrict__ b0,
                const float* __restrict__ W1, const float* __restrict__ b1,
                const float* __restrict__ W2, const float* __restrict__ b2,
                float* __restrict__ out)
{
    __shared__ float sW0[7 * 512];
    __shared__ float sH1[MT * 512];
    __shared__ float sQ[MT][8];
    __shared__ float sQd[MT][8];
    __shared__ float sRed[8][24];
    __shared__ float sOut[24];

    const int tid = threadIdx.x;          // 0..511
    const int m0  = blockIdx.x * MT;      // sample base

    // stage W0 + inputs
    for (int idx = tid; idx < 7 * 512; idx += 512) sW0[idx] = W0[idx];
    if (tid < MT * 14) {
        int m = tid / 14, c = tid % 14;
        float v = x[(m0 + m) * 14 + c];
        if (c < 7) sQ[m][c] = v; else sQd[m][c - 7] = v;
    }
    __syncthreads();

    // layer 0: h1 = sigmoid(q W0 + b0)
    for (int idx = tid; idx < MT * 512; idx += 512) {
        int m = idx >> 9, n2 = idx & 511;
        float z = b0[n2];
        #pragma unroll
        for (int i = 0; i < 7; i++) z = fmaf(sQ[m][i], sW0[i * 512 + n2], z);
        sH1[idx] = sig(z);
    }
    __syncthreads();

    // layer 1: thread owns neuron n; accumulate z2 and 7 tangent dots for MT samples
    const int n = tid;
    float z2[MT];
    float U[MT][7];
    {
        float bb = b1[n];
        #pragma unroll
        for (int m = 0; m < MT; m++) {
            z2[m] = bb;
            #pragma unroll
            for (int i = 0; i < 7; i++) U[m][i] = 0.0f;
        }
    }
    const float4* sH14 = reinterpret_cast<const float4*>(sH1);
    const float4* sW04 = reinterpret_cast<const float4*>(sW0);
    for (int k4 = 0; k4 < 128; k4++) {
        const int kb = k4 << 2;
        float wj[4];
        wj[0] = W1[(kb + 0) * 512 + n];
        wj[1] = W1[(kb + 1) * 512 + n];
        wj[2] = W1[(kb + 2) * 512 + n];
        wj[3] = W1[(kb + 3) * 512 + n];
        float w0a[4][7];
        #pragma unroll
        for (int i = 0; i < 7; i++) {
            float4 t = sW04[i * 128 + k4];      // broadcast read
            w0a[0][i] = t.x; w0a[1][i] = t.y; w0a[2][i] = t.z; w0a[3][i] = t.w;
        }
        #pragma unroll
        for (int m = 0; m < MT; m++) {
            float4 h4 = sH14[m * 128 + k4];     // broadcast read
            float hh[4] = {h4.x, h4.y, h4.z, h4.w};
            #pragma unroll
            for (int j = 0; j < 4; j++) {
                float h = hh[j], w = wj[j];
                float d = fmaf(-h, h, h);       // sigma'
                z2[m] = fmaf(h, w, z2[m]);
                float g = d * w;
                #pragma unroll
                for (int i = 0; i < 7; i++) U[m][i] = fmaf(g, w0a[j][i], U[m][i]);
            }
        }
    }

    // layer 2 + reduction over n (512 threads)
    const int lane = tid & 63;
    const int wave = tid >> 6;
    const float w2_0 = W2[n * 3 + 0], w2_1 = W2[n * 3 + 1], w2_2 = W2[n * 3 + 2];

    for (int m = 0; m < MT; m++) {
        float h2 = sig(z2[m]);
        float d2 = fmaf(-h2, h2, h2);
        float p[24];
        p[0] = h2 * w2_0; p[1] = h2 * w2_1; p[2] = h2 * w2_2;
        #pragma unroll
        for (int i = 0; i < 7; i++) {
            float t = d2 * U[m][i];
            p[3 + i]  = t * w2_0;    // J[0][i]
            p[10 + i] = t * w2_1;    // J[1][i]
            p[17 + i] = t * w2_2;    // J[2][i]
        }
        #pragma unroll
        for (int o = 0; o < 24; o++) {
            float v = p[o];
            #pragma unroll
            for (int off = 32; off > 0; off >>= 1) v += __shfl_down(v, off);
            if (lane == 0) sRed[wave][o] = v;
        }
        __syncthreads();
        if (tid < 24) {
            float v = 0.0f;
            #pragma unroll
            for (int w = 0; w < 8; w++) v += sRed[w][tid];
            if (tid < 3) v += b2[tid];
            sOut[tid] = v;
        }
        __syncthreads();
        const int M = m0 + m;
        if (tid < 3) {
            int j = tid;
            float y = sOut[j];
            out[OUT0_OFF + M * 18 + j] = y;          // P
            out[OUTA_OFF + M * 6 + j]  = y;          // out_angles P part
            float vel = 0.0f;
            #pragma unroll
            for (int i = 0; i < 7; i++) vel = fmaf(sOut[3 + j * 7 + i], sQd[m][i], vel);
            out[OUT0_OFF + M * 18 + 9 + j] = vel;    // vel
        } else if (tid >= 3 && tid < 24) {
            int j = (tid - 3) / 7, i = (tid - 3) % 7;
            float Jv = sOut[tid];
            out[JTOT_OFF + M * 63 + j * 7 + i] = Jv;
            out[JANG_OFF + M * 42 + j * 7 + i] = Jv;
        }
        __syncthreads();
    }
}

// ---------------- rpy heads: 7 -> 256 -> 256 -> 2, blockIdx.y = head ----------------
__global__ __launch_bounds__(256, 2)
void rpy_kernel(const float* __restrict__ x,
                const float* __restrict__ rW0, const float* __restrict__ rb0,
                const float* __restrict__ rW1, const float* __restrict__ rb1,
                const float* __restrict__ rW2, const float* __restrict__ rb2,
                const float* __restrict__ pW0, const float* __restrict__ pb0,
                const float* __restrict__ pW1, const float* __restrict__ pb1,
                const float* __restrict__ pW2, const float* __restrict__ pb2,
                const float* __restrict__ yW0, const float* __restrict__ yb0,
                const float* __restrict__ yW1, const float* __restrict__ yb1,
                const float* __restrict__ yW2, const float* __restrict__ yb2,
                float* __restrict__ out)
{
    __shared__ float sW0[7 * 256];
    __shared__ float sH1[MT * 256];
    __shared__ float sQ[MT][8];
    __shared__ float sQd[MT][8];
    __shared__ float sRed[4][16];
    __shared__ float sOut[16];
    __shared__ float sHead[8];

    const int tid = threadIdx.x;          // 0..255
    const int m0  = blockIdx.x * MT;
    const int h   = blockIdx.y;           // 0=roll 1=pitch 2=yaw

    const float* W0 = (h == 0) ? rW0 : (h == 1) ? pW0 : yW0;
    const float* b0 = (h == 0) ? rb0 : (h == 1) ? pb0 : yb0;
    const float* W1 = (h == 0) ? rW1 : (h == 1) ? pW1 : yW1;
    const float* b1 = (h == 0) ? rb1 : (h == 1) ? pb1 : yb1;
    const float* W2 = (h == 0) ? rW2 : (h == 1) ? pW2 : yW2;
    const float* b2 = (h == 0) ? rb2 : (h == 1) ? pb2 : yb2;

    for (int idx = tid; idx < 7 * 256; idx += 256) sW0[idx] = W0[idx];
    if (tid < MT * 14) {
        int m = tid / 14, c = tid % 14;
        float v = x[(m0 + m) * 14 + c];
        if (c < 7) sQ[m][c] = v; else sQd[m][c - 7] = v;
    }
    __syncthreads();

    for (int idx = tid; idx < MT * 256; idx += 256) {
        int m = idx >> 8, n2 = idx & 255;
        float z = b0[n2];
        #pragma unroll
        for (int i = 0; i < 7; i++) z = fmaf(sQ[m][i], sW0[i * 256 + n2], z);
        sH1[idx] = sig(z);
    }
    __syncthreads();

    const int n = tid;
    float z2[MT];
    float U[MT][7];
    {
        float bb = b1[n];
        #pragma unroll
        for (int m = 0; m < MT; m++) {
            z2[m] = bb;
            #pragma unroll
            for (int i = 0; i < 7; i++) U[m][i] = 0.0f;
        }
    }
    const float4* sH14 = reinterpret_cast<const float4*>(sH1);
    const float4* sW04 = reinterpret_cast<const float4*>(sW0);
    for (int k4 = 0; k4 < 64; k4++) {
        const int kb = k4 << 2;
        float wj[4];
        wj[0] = W1[(kb + 0) * 256 + n];
        wj[1] = W1[(kb + 1) * 256 + n];
        wj[2] = W1[(kb + 2) * 256 + n];
        wj[3] = W1[(kb + 3) * 256 + n];
        float w0a[4][7];
        #pragma unroll
        for (int i = 0; i < 7; i++) {
            float4 t = sW04[i * 64 + k4];
            w0a[0][i] = t.x; w0a[1][i] = t.y; w0a[2][i] = t.z; w0a[3][i] = t.w;
        }
        #pragma unroll
        for (int m = 0; m < MT; m++) {
            float4 h4 = sH14[m * 64 + k4];
            float hh[4] = {h4.x, h4.y, h4.z, h4.w};
            #pragma unroll
            for (int j = 0; j < 4; j++) {
                float hv = hh[j], w = wj[j];
                float d = fmaf(-hv, hv, hv);
                z2[m] = fmaf(hv, w, z2[m]);
                float g = d * w;
                #pragma unroll
                for (int i = 0; i < 7; i++) U[m][i] = fmaf(g, w0a[j][i], U[m][i]);
            }
        }
    }

    const int lane = tid & 63;
    const int wave = tid >> 6;
    const float w2a = W2[n * 2 + 0], w2b = W2[n * 2 + 1];

    for (int m = 0; m < MT; m++) {
        float h2 = sig(z2[m]);
        float d2 = fmaf(-h2, h2, h2);
        float p[16];
        p[0] = h2 * w2a; p[1] = h2 * w2b;
        #pragma unroll
        for (int i = 0; i < 7; i++) {
            float t = d2 * U[m][i];
            p[2 + i] = t * w2a;   // raw J2[0][i]
            p[9 + i] = t * w2b;   // raw J2[1][i]
        }
        #pragma unroll
        for (int o = 0; o < 16; o++) {
            float v = p[o];
            #pragma unroll
            for (int off = 32; off > 0; off >>= 1) v += __shfl_down(v, off);
            if (lane == 0) sRed[wave][o] = v;
        }
        __syncthreads();
        if (tid < 16) {
            float v = sRed[0][tid] + sRed[1][tid] + sRed[2][tid] + sRed[3][tid];
            if (tid < 2) v += b2[tid];
            sOut[tid] = v;
        }
        __syncthreads();
        if (tid == 0) {
            float y0 = sOut[0], y1 = sOut[1];
            float s = sinf(y0), c = cosf(y1);
            sHead[0] = s;
            sHead[1] = c;
            sHead[2] = atan2f(s, c);
            sHead[3] = cosf(y0);          // d s / d y0
            sHead[4] = -sinf(y1);         // d c / d y1
            sHead[5] = 1.0f / fmaf(s, s, c * c);
        }
        __syncthreads();
        const int M = m0 + m;
        const float s = sHead[0], c = sHead[1];
        const float f0 = sHead[3], f1 = sHead[4], inv = sHead[5];
        if (tid < 7) {
            int i = tid;
            float r0 = f0 * sOut[2 + i];               // d s / d q_i
            float r1 = f1 * sOut[9 + i];               // d c / d q_i
            float r2 = (c * r0 - s * r1) * inv;        // d atan2 / d q_i
            out[JTOT_OFF + M * 63 + (3 + h) * 7 + i] = r0;
            out[JTOT_OFF + M * 63 + (6 + h) * 7 + i] = r1;
            out[JANG_OFF + M * 42 + (3 + h) * 7 + i] = r2;
        } else if (tid == 8) {
            out[OUT0_OFF + M * 18 + 3 + h] = s;
            out[OUT0_OFF + M * 18 + 6 + h] = c;
            out[OUTA_OFF + M * 6 + 3 + h]  = sHead[2];
        } else if (tid == 9) {
            float v0 = 0.0f, v1 = 0.0f;
            #pragma unroll
            for (int i = 0; i < 7; i++) {
                v0 = fmaf(f0 * sOut[2 + i], sQd[m][i], v0);
                v1 = fmaf(f1 * sOut[9 + i], sQd[m][i], v1);
            }
            out[OUT0_OFF + M * 18 + 12 + h] = v0;
            out[OUT0_OFF + M * 18 + 15 + h] = v1;
        }
        __syncthreads();
    }
}

extern "C" void kernel_launch(void* const* d_in, const int* in_sizes, int n_in,
                              void* d_out, int out_size, void* d_ws, size_t ws_size,
                              hipStream_t stream) {
    (void)in_sizes; (void)n_in; (void)d_ws; (void)ws_size; (void)out_size;
    const float* x   = (const float*)d_in[0];
    float* out = (float*)d_out;

    pos_kernel<<<dim3(NSAMP / MT), 512, 0, stream>>>(
        x,
        (const float*)d_in[1], (const float*)d_in[2],
        (const float*)d_in[3], (const float*)d_in[4],
        (const float*)d_in[5], (const float*)d_in[6],
        out);

    rpy_kernel<<<dim3(NSAMP / MT, 3), 256, 0, stream>>>(
        x,
        (const float*)d_in[7],  (const float*)d_in[8],
        (const float*)d_in[9],  (const float*)d_in[10],
        (const float*)d_in[11], (const float*)d_in[12],
        (const float*)d_in[13], (const float*)d_in[14],
        (const float*)d_in[15], (const float*)d_in[16],
        (const float*)d_in[17], (const float*)d_in[18],
        (const float*)d_in[19], (const float*)d_in[20],
        (const float*)d_in[21], (const float*)d_in[22],
        (const float*)d_in[23], (const float*)d_in[24],
        out);
}

// Round 2
// 609.962 us; speedup vs baseline: 3.8153x; 3.8153x over previous
//
#include <hip/hip_runtime.h>
#include <math.h>

typedef __attribute__((ext_vector_type(8))) short short8;
typedef __attribute__((ext_vector_type(4))) float floatx4;

__device__ __forceinline__ float sig(float z) { return 1.0f / (1.0f + __expf(-z)); }

__device__ __forceinline__ unsigned short f2bf(float f) {
    unsigned u = __float_as_uint(f);
    u = (u + 0x7FFFu + ((u >> 16) & 1u)) >> 16;   // RNE
    return (unsigned short)u;
}

// Convert H x H fp32 weight (row-major [k][n]) into bf16 pre-swizzled into
// MFMA 16x16x32 B-fragment order: block = (n>>4)*(H/32) + (k>>5),
// lane = ((k>>3)&3)*16 + (n&15), j = k&7; dst[(block*64+lane)*8 + j].
__global__ void convert_w1(const float* __restrict__ src, unsigned short* __restrict__ dst,
                           int H, int logH) {
    int idx = blockIdx.x * 256 + threadIdx.x;
    if (idx >= H * H) return;
    int n = idx & (H - 1), k = idx >> logH;
    int KT = H >> 5;
    int blk = (n >> 4) * KT + (k >> 5);
    int lane = ((k >> 3) & 3) * 16 + (n & 15);
    int j = k & 7;
    dst[(blk * 64 + lane) * 8 + j] = f2bf(src[idx]);
}

// ---------------- pos net: 7 -> 512 -> 512 -> 3 ----------------
// Block: 8 samples, 256 threads (4 waves). A = 64 rows x 512 (h1 + 7 tangent rows
// per sample) in LDS in A-fragment order. Wave w owns cols [w*128, w*128+128).
__global__ __launch_bounds__(256, 1)
void pos_mfma(const float* __restrict__ x,
              const float* __restrict__ W0, const float* __restrict__ b0,
              const float* __restrict__ b1,
              const float* __restrict__ W2, const float* __restrict__ b2,
              const unsigned short* __restrict__ wsW1,
              float* __restrict__ out, int ns)
{
    extern __shared__ unsigned short sA[];      // 32768 shorts = 64 KB (dynamic)
    __shared__ float sW0[3584];
    __shared__ float sB0[512];
    __shared__ float sB1[512];
    __shared__ float sW2[1536];
    __shared__ float sQ[8][8];
    __shared__ float sQd[8][8];
    __shared__ float sScr[4][64][17];
    __shared__ float sAcc[4][8][8][3];
    __shared__ float sSum[8][8][3];

    const int tid = threadIdx.x;
    const int m0  = blockIdx.x * 8;

    for (int i = tid; i < 3584; i += 256) sW0[i] = W0[i];
    for (int i = tid; i < 512;  i += 256) { sB0[i] = b0[i]; sB1[i] = b1[i]; }
    for (int i = tid; i < 1536; i += 256) sW2[i] = W2[i];
    if (tid < 112) {
        int m = tid / 14, c = tid % 14;
        float v = x[(m0 + m) * 14 + c];
        if (c < 7) sQ[m][c] = v; else sQd[m][c - 7] = v;
    }
    __syncthreads();

    // Build A (h1 row + 7 tangent rows) directly in A-fragment-swizzled layout.
    for (int idx = tid; idx < 4096; idx += 256) {
        int s = idx >> 9, k = idx & 511;
        float z = sB0[k];
        #pragma unroll
        for (int i = 0; i < 7; i++) z = fmaf(sQ[s][i], sW0[i * 512 + k], z);
        float h = sig(z);
        float d = h - h * h;
        int kt = k >> 5, kq = (k >> 3) & 3, j = k & 7;
        int r = s * 8;
        sA[((r >> 4) * 16 + kt) * 512 + (kq * 16 + (r & 15)) * 8 + j] = f2bf(h);
        #pragma unroll
        for (int i = 0; i < 7; i++) {
            int rr = r + 1 + i;
            sA[((rr >> 4) * 16 + kt) * 512 + (kq * 16 + (rr & 15)) * 8 + j] =
                f2bf(d * sW0[i * 512 + k]);
        }
    }
    __syncthreads();

    const int w = tid >> 6, lane = tid & 63;
    const int quad = lane >> 4, col = lane & 15;
    const int s_ep = lane >> 3, i_ep = lane & 7;
    float accO0 = 0.f, accO1 = 0.f, accO2 = 0.f;
    const floatx4 z4 = {0.f, 0.f, 0.f, 0.f};

    for (int ct = 0; ct < 8; ++ct) {
        floatx4 acc[4];
        #pragma unroll
        for (int rt = 0; rt < 4; ++rt) acc[rt] = z4;
        const int ctg = w * 8 + ct;
        const short8* bp = (const short8*)wsW1 + (ctg * 16) * 64 + lane;
        #pragma unroll
        for (int kt = 0; kt < 16; ++kt) {
            short8 bfrag = bp[kt * 64];
            #pragma unroll
            for (int rt = 0; rt < 4; ++rt) {
                short8 afrag = *(const short8*)&sA[(rt * 16 + kt) * 512 + lane * 8];
                acc[rt] = __builtin_amdgcn_mfma_f32_16x16x32_bf16(afrag, bfrag, acc[rt], 0, 0, 0);
            }
        }
        #pragma unroll
        for (int rt = 0; rt < 4; ++rt)
            #pragma unroll
            for (int r = 0; r < 4; ++r)
                sScr[w][rt * 16 + quad * 4 + r][col] = acc[rt][r];
        __syncthreads();
        const int nbase = w * 128 + ct * 16;
        #pragma unroll
        for (int t = 0; t < 16; ++t) {
            int n = nbase + t;
            float z2v = sScr[w][s_ep * 8][t] + sB1[n];
            float h2 = sig(z2v);
            float g;
            if (i_ep == 0) g = h2;
            else { float uv = sScr[w][s_ep * 8 + i_ep][t]; g = (h2 - h2 * h2) * uv; }
            accO0 = fmaf(g, sW2[n * 3 + 0], accO0);
            accO1 = fmaf(g, sW2[n * 3 + 1], accO1);
            accO2 = fmaf(g, sW2[n * 3 + 2], accO2);
        }
        __syncthreads();
    }
    sAcc[w][s_ep][i_ep][0] = accO0;
    sAcc[w][s_ep][i_ep][1] = accO1;
    sAcc[w][s_ep][i_ep][2] = accO2;
    __syncthreads();

    const long JTOT = (long)ns * 18, OUTA = (long)ns * 81, JANG = (long)ns * 87;
    if (tid < 192) {
        int s = tid / 24, rem = tid % 24, i = rem / 3, j = rem % 3;
        float v = sAcc[0][s][i][j] + sAcc[1][s][i][j] + sAcc[2][s][i][j] + sAcc[3][s][i][j];
        long M = m0 + s;
        if (i == 0) { v += b2[j]; out[M * 18 + j] = v; out[OUTA + M * 6 + j] = v; }
        else        { out[JTOT + M * 63 + j * 7 + (i - 1)] = v;
                      out[JANG + M * 42 + j * 7 + (i - 1)] = v; }
        sSum[s][i][j] = v;
    }
    __syncthreads();
    if (tid < 24) {
        int s = tid / 3, j = tid % 3;
        float vel = 0.f;
        #pragma unroll
        for (int i = 0; i < 7; i++) vel = fmaf(sSum[s][i + 1][j], sQd[s][i], vel);
        out[(long)(m0 + s) * 18 + 9 + j] = vel;
    }
}

// ---------------- rpy heads: 7 -> 256 -> 256 -> 2, blockIdx.y = head ----------------
__global__ __launch_bounds__(256, 2)
void rpy_mfma(const float* __restrict__ x,
              const float* __restrict__ rW0, const float* __restrict__ rb0,
              const float* __restrict__ rb1,
              const float* __restrict__ rW2, const float* __restrict__ rb2,
              const float* __restrict__ pW0, const float* __restrict__ pb0,
              const float* __restrict__ pb1,
              const float* __restrict__ pW2, const float* __restrict__ pb2,
              const float* __restrict__ yW0, const float* __restrict__ yb0,
              const float* __restrict__ yb1,
              const float* __restrict__ yW2, const float* __restrict__ yb2,
              const unsigned short* __restrict__ wsBase,
              float* __restrict__ out, int ns)
{
    extern __shared__ unsigned short sA[];      // 16384 shorts = 32 KB (dynamic)
    __shared__ float sW0[1792];
    __shared__ float sB0[256];
    __shared__ float sB1[256];
    __shared__ float sW2[512];
    __shared__ float sQ[8][8];
    __shared__ float sQd[8][8];
    __shared__ float sScr[4][64][17];
    __shared__ float sAcc[4][8][8][2];
    __shared__ float sSum[8][8][2];

    const int tid = threadIdx.x;
    const int m0  = blockIdx.x * 8;
    const int h   = blockIdx.y;

    const float* W0 = (h == 0) ? rW0 : (h == 1) ? pW0 : yW0;
    const float* b0 = (h == 0) ? rb0 : (h == 1) ? pb0 : yb0;
    const float* b1 = (h == 0) ? rb1 : (h == 1) ? pb1 : yb1;
    const float* W2 = (h == 0) ? rW2 : (h == 1) ? pW2 : yW2;
    const float* b2 = (h == 0) ? rb2 : (h == 1) ? pb2 : yb2;
    const unsigned short* wsW1 = wsBase + 262144 + h * 65536;   // short offsets

    for (int i = tid; i < 1792; i += 256) sW0[i] = W0[i];
    if (tid < 256) { sB0[tid] = b0[tid]; sB1[tid] = b1[tid]; }
    for (int i = tid; i < 512; i += 256) sW2[i] = W2[i];
    if (tid < 112) {
        int m = tid / 14, c = tid % 14;
        float v = x[(m0 + m) * 14 + c];
        if (c < 7) sQ[m][c] = v; else sQd[m][c - 7] = v;
    }
    __syncthreads();

    for (int idx = tid; idx < 2048; idx += 256) {
        int s = idx >> 8, k = idx & 255;
        float z = sB0[k];
        #pragma unroll
        for (int i = 0; i < 7; i++) z = fmaf(sQ[s][i], sW0[i * 256 + k], z);
        float hh = sig(z);
        float d = hh - hh * hh;
        int kt = k >> 5, kq = (k >> 3) & 3, j = k & 7;
        int r = s * 8;
        sA[((r >> 4) * 8 + kt) * 512 + (kq * 16 + (r & 15)) * 8 + j] = f2bf(hh);
        #pragma unroll
        for (int i = 0; i < 7; i++) {
            int rr = r + 1 + i;
            sA[((rr >> 4) * 8 + kt) * 512 + (kq * 16 + (rr & 15)) * 8 + j] =
                f2bf(d * sW0[i * 256 + k]);
        }
    }
    __syncthreads();

    const int w = tid >> 6, lane = tid & 63;
    const int quad = lane >> 4, col = lane & 15;
    const int s_ep = lane >> 3, i_ep = lane & 7;
    float accO0 = 0.f, accO1 = 0.f;
    const floatx4 z4 = {0.f, 0.f, 0.f, 0.f};

    for (int ct = 0; ct < 4; ++ct) {
        floatx4 acc[4];
        #pragma unroll
        for (int rt = 0; rt < 4; ++rt) acc[rt] = z4;
        const int ctg = w * 4 + ct;
        const short8* bp = (const short8*)wsW1 + (ctg * 8) * 64 + lane;
        #pragma unroll
        for (int kt = 0; kt < 8; ++kt) {
            short8 bfrag = bp[kt * 64];
            #pragma unroll
            for (int rt = 0; rt < 4; ++rt) {
                short8 afrag = *(const short8*)&sA[(rt * 8 + kt) * 512 + lane * 8];
                acc[rt] = __builtin_amdgcn_mfma_f32_16x16x32_bf16(afrag, bfrag, acc[rt], 0, 0, 0);
            }
        }
        #pragma unroll
        for (int rt = 0; rt < 4; ++rt)
            #pragma unroll
            for (int r = 0; r < 4; ++r)
                sScr[w][rt * 16 + quad * 4 + r][col] = acc[rt][r];
        __syncthreads();
        const int nbase = w * 64 + ct * 16;
        #pragma unroll
        for (int t = 0; t < 16; ++t) {
            int n = nbase + t;
            float z2v = sScr[w][s_ep * 8][t] + sB1[n];
            float h2 = sig(z2v);
            float g;
            if (i_ep == 0) g = h2;
            else { float uv = sScr[w][s_ep * 8 + i_ep][t]; g = (h2 - h2 * h2) * uv; }
            accO0 = fmaf(g, sW2[n * 2 + 0], accO0);
            accO1 = fmaf(g, sW2[n * 2 + 1], accO1);
        }
        __syncthreads();
    }
    sAcc[w][s_ep][i_ep][0] = accO0;
    sAcc[w][s_ep][i_ep][1] = accO1;
    __syncthreads();

    const long JTOT = (long)ns * 18, OUTA = (long)ns * 81, JANG = (long)ns * 87;
    if (tid < 128) {
        int s = tid >> 4, rem = tid & 15, i = rem >> 1, j = rem & 1;
        float v = sAcc[0][s][i][j] + sAcc[1][s][i][j] + sAcc[2][s][i][j] + sAcc[3][s][i][j];
        if (i == 0) v += b2[j];
        sSum[s][i][j] = v;
    }
    __syncthreads();
    if (tid < 8) {
        int s = tid;
        long M = m0 + s;
        float y0 = sSum[s][0][0], y1 = sSum[s][0][1];
        float sv = sinf(y0), cv = cosf(y1);
        out[M * 18 + 3 + h] = sv;
        out[M * 18 + 6 + h] = cv;
        out[OUTA + M * 6 + 3 + h] = atan2f(sv, cv);
        float f0 = cosf(y0), f1 = -sinf(y1);
        float inv = 1.0f / fmaf(sv, sv, cv * cv);
        float v0 = 0.f, v1 = 0.f;
        #pragma unroll
        for (int i = 0; i < 7; i++) {
            float r0 = f0 * sSum[s][i + 1][0];
            float r1 = f1 * sSum[s][i + 1][1];
            out[JTOT + M * 63 + (3 + h) * 7 + i] = r0;
            out[JTOT + M * 63 + (6 + h) * 7 + i] = r1;
            out[JANG + M * 42 + (3 + h) * 7 + i] = (cv * r0 - sv * r1) * inv;
            v0 = fmaf(r0, sQd[s][i], v0);
            v1 = fmaf(r1, sQd[s][i], v1);
        }
        out[M * 18 + 12 + h] = v0;
        out[M * 18 + 15 + h] = v1;
    }
}

extern "C" void kernel_launch(void* const* d_in, const int* in_sizes, int n_in,
                              void* d_out, int out_size, void* d_ws, size_t ws_size,
                              hipStream_t stream) {
    (void)n_in; (void)out_size; (void)ws_size;
    const float* x = (const float*)d_in[0];
    float* out = (float*)d_out;
    unsigned short* ws = (unsigned short*)d_ws;
    const int ns = in_sizes[0] / 14;

    // pre-swizzle W1 matrices to bf16 fragment layout (ws: pos@0, r/p/y @ 262144+...)
    convert_w1<<<dim3((512 * 512) / 256), 256, 0, stream>>>((const float*)d_in[3],  ws,          512, 9);
    convert_w1<<<dim3((256 * 256) / 256), 256, 0, stream>>>((const float*)d_in[9],  ws + 262144, 256, 8);
    convert_w1<<<dim3((256 * 256) / 256), 256, 0, stream>>>((const float*)d_in[15], ws + 327680, 256, 8);
    convert_w1<<<dim3((256 * 256) / 256), 256, 0, stream>>>((const float*)d_in[21], ws + 393216, 256, 8);

    pos_mfma<<<dim3(ns / 8), 256, 65536, stream>>>(
        x,
        (const float*)d_in[1], (const float*)d_in[2],
        (const float*)d_in[4],
        (const float*)d_in[5], (const float*)d_in[6],
        ws, out, ns);

    rpy_mfma<<<dim3(ns / 8, 3), 256, 32768, stream>>>(
        x,
        (const float*)d_in[7],  (const float*)d_in[8],  (const float*)d_in[10],
        (const float*)d_in[11], (const float*)d_in[12],
        (const float*)d_in[13], (const float*)d_in[14], (const float*)d_in[16],
        (const float*)d_in[17], (const float*)d_in[18],
        (const float*)d_in[19], (const float*)d_in[20], (const float*)d_in[22],
        (const float*)d_in[23], (const float*)d_in[24],
        ws, out, ns);
}

// Round 3
// 371.244 us; speedup vs baseline: 6.2687x; 1.6430x over previous
//
#include <hip/hip_runtime.h>
#include <math.h>

typedef __attribute__((ext_vector_type(8))) short short8;
typedef __attribute__((ext_vector_type(4))) float floatx4;

__device__ __forceinline__ float sig(float z) { return 1.0f / (1.0f + __expf(-z)); }

__device__ __forceinline__ unsigned short f2bf(float f) {
    unsigned u = __float_as_uint(f);
    u = (u + 0x7FFFu + ((u >> 16) & 1u)) >> 16;   // RNE
    return (unsigned short)u;
}

// Convert H x H fp32 weight (row-major [k][n]) into bf16 pre-swizzled into
// MFMA 16x16x32 B-fragment order: block = (n>>4)*(H/32) + (k>>5),
// lane = ((k>>3)&3)*16 + (n&15), j = k&7; dst[(block*64+lane)*8 + j].
__global__ void convert_w1(const float* __restrict__ src, unsigned short* __restrict__ dst,
                           int H, int logH) {
    int idx = blockIdx.x * 256 + threadIdx.x;
    if (idx >= H * H) return;
    int n = idx & (H - 1), k = idx >> logH;
    int KT = H >> 5;
    int blk = (n >> 4) * KT + (k >> 5);
    int lane = ((k >> 3) & 3) * 16 + (n & 15);
    int j = k & 7;
    dst[(blk * 64 + lane) * 8 + j] = f2bf(src[idx]);
}

// ---------------- pos net: 7 -> 512 -> 512 -> 3 ----------------
// 8 samples/block (M=64 rows), 256 threads. Wave w: row-pair rta=(w&1)*2, N-half nh=w>>1.
// A-frags held in registers (2 x 16 frags); B streamed from pre-swizzled global (L1/L2).
__global__ __launch_bounds__(256, 2)
void pos_mfma(const float* __restrict__ x,
              const float* __restrict__ W0, const float* __restrict__ b0,
              const float* __restrict__ b1,
              const float* __restrict__ W2, const float* __restrict__ b2,
              const unsigned short* __restrict__ wsW1,
              float* __restrict__ out, int ns)
{
    extern __shared__ unsigned short sA[];      // 32768 shorts = 64 KB
    __shared__ float sB0[512];
    __shared__ float sB1[512];
    __shared__ float sW2[1536];
    __shared__ float sQ[8][8];
    __shared__ float sQd[8][8];
    __shared__ float sAcc[2][64][3];
    __shared__ float sSum[64][3];

    const int tid = threadIdx.x;
    const int m0  = blockIdx.x * 8;

    for (int i = tid; i < 512;  i += 256) { sB0[i] = b0[i]; sB1[i] = b1[i]; }
    for (int i = tid; i < 1536; i += 256) sW2[i] = W2[i];
    if (tid < 112) {
        int m = tid / 14, c = tid % 14;
        float v = x[(m0 + m) * 14 + c];
        if (c < 7) sQ[m][c] = v; else sQd[m][c - 7] = v;
    }
    __syncthreads();

    // Build A (h1 row + 7 tangent rows per sample) in fragment order, b128 stores.
    const float4* W04 = (const float4*)W0;
    #pragma unroll
    for (int t = 0; t < 2; ++t) {
        int item = tid + t * 256;            // 512 items: (s, k8)
        int s = item >> 6, k8 = item & 63;   // k8: group of 8 k
        float q[7], w0v[7][8];
        #pragma unroll
        for (int i = 0; i < 7; i++) {
            q[i] = sQ[s][i];
            float4 a = W04[i * 128 + k8 * 2], b4 = W04[i * 128 + k8 * 2 + 1];
            w0v[i][0]=a.x; w0v[i][1]=a.y; w0v[i][2]=a.z; w0v[i][3]=a.w;
            w0v[i][4]=b4.x; w0v[i][5]=b4.y; w0v[i][6]=b4.z; w0v[i][7]=b4.w;
        }
        float hv[8], dv[8];
        #pragma unroll
        for (int jj = 0; jj < 8; jj++) {
            float z = sB0[k8 * 8 + jj];
            #pragma unroll
            for (int i = 0; i < 7; i++) z = fmaf(q[i], w0v[i][jj], z);
            float h = sig(z);
            hv[jj] = h; dv[jj] = h - h * h;
        }
        int kt = k8 >> 2, kq = k8 & 3;
        int rr0 = s * 8;
        {
            short8 v;
            #pragma unroll
            for (int jj = 0; jj < 8; jj++) v[jj] = (short)f2bf(hv[jj]);
            *(short8*)&sA[((rr0 >> 4) * 16 + kt) * 512 + (kq * 16 + (rr0 & 15)) * 8] = v;
        }
        #pragma unroll
        for (int i = 0; i < 7; i++) {
            int rr = rr0 + 1 + i;
            short8 v;
            #pragma unroll
            for (int jj = 0; jj < 8; jj++) v[jj] = (short)f2bf(dv[jj] * w0v[i][jj]);
            *(short8*)&sA[((rr >> 4) * 16 + kt) * 512 + (kq * 16 + (rr & 15)) * 8] = v;
        }
    }
    __syncthreads();

    const int w = tid >> 6, lane = tid & 63;
    const int rta = (w & 1) * 2, nh = w >> 1;
    const int quad = lane >> 4, col = lane & 15;
    const int srcl = lane & 47;

    short8 afr[2][16];
    #pragma unroll
    for (int rt2 = 0; rt2 < 2; ++rt2)
        #pragma unroll
        for (int kt = 0; kt < 16; ++kt)
            afr[rt2][kt] = *(const short8*)&sA[((rta + rt2) * 16 + kt) * 512 + lane * 8];

    float ep[2][4][3];
    #pragma unroll
    for (int a = 0; a < 2; a++) for (int b = 0; b < 4; b++) for (int c = 0; c < 3; c++) ep[a][b][c] = 0.f;
    const floatx4 z4 = {0.f, 0.f, 0.f, 0.f};

    for (int ct = 0; ct < 16; ++ct) {
        floatx4 acc[2] = {z4, z4};
        const short8* bp = (const short8*)wsW1 + (size_t)((nh * 16 + ct) * 16) * 64 + lane;
        #pragma unroll
        for (int kt = 0; kt < 16; ++kt) {
            short8 bf = bp[kt * 64];
            acc[0] = __builtin_amdgcn_mfma_f32_16x16x32_bf16(afr[0][kt], bf, acc[0], 0, 0, 0);
            acc[1] = __builtin_amdgcn_mfma_f32_16x16x32_bf16(afr[1][kt], bf, acc[1], 0, 0, 0);
        }
        const int n = nh * 256 + ct * 16 + col;
        const float b1n = sB1[n];
        const float w20 = sW2[n * 3], w21 = sW2[n * 3 + 1], w22 = sW2[n * 3 + 2];
        #pragma unroll
        for (int rt2 = 0; rt2 < 2; ++rt2) {
            float z2c = __shfl(acc[rt2][0], srcl);
            float h2 = sig(z2c + b1n);
            float d2 = h2 - h2 * h2;
            #pragma unroll
            for (int r = 0; r < 4; ++r) {
                float g = ((quad & 1) == 0 && r == 0) ? h2 : d2 * acc[rt2][r];
                ep[rt2][r][0] = fmaf(g, w20, ep[rt2][r][0]);
                ep[rt2][r][1] = fmaf(g, w21, ep[rt2][r][1]);
                ep[rt2][r][2] = fmaf(g, w22, ep[rt2][r][2]);
            }
        }
    }

    // reduce over the 16 columns (lane bits 0-3)
    #pragma unroll
    for (int mask = 1; mask <= 8; mask <<= 1)
        #pragma unroll
        for (int a = 0; a < 2; a++)
            #pragma unroll
            for (int b = 0; b < 4; b++)
                #pragma unroll
                for (int c = 0; c < 3; c++)
                    ep[a][b][c] += __shfl_xor(ep[a][b][c], mask);
    if (col == 0) {
        #pragma unroll
        for (int rt2 = 0; rt2 < 2; ++rt2)
            #pragma unroll
            for (int r = 0; r < 4; ++r) {
                int row = (rta + rt2) * 16 + quad * 4 + r;
                sAcc[nh][row][0] = ep[rt2][r][0];
                sAcc[nh][row][1] = ep[rt2][r][1];
                sAcc[nh][row][2] = ep[rt2][r][2];
            }
    }
    __syncthreads();

    const long JTOT = (long)ns * 18, OUTA = (long)ns * 81, JANG = (long)ns * 87;
    if (tid < 192) {
        int row = tid / 3, j = tid % 3;
        float v = sAcc[0][row][j] + sAcc[1][row][j];
        int s = row >> 3, i = row & 7;
        long M = m0 + s;
        if (i == 0) { v += b2[j]; out[M * 18 + j] = v; out[OUTA + M * 6 + j] = v; }
        else        { out[JTOT + M * 63 + j * 7 + (i - 1)] = v;
                      out[JANG + M * 42 + j * 7 + (i - 1)] = v; }
        sSum[row][j] = v;
    }
    __syncthreads();
    if (tid < 24) {
        int s = tid / 3, j = tid % 3;
        float vel = 0.f;
        #pragma unroll
        for (int i = 0; i < 7; i++) vel = fmaf(sSum[s * 8 + 1 + i][j], sQd[s][i], vel);
        out[(long)(m0 + s) * 18 + 9 + j] = vel;
    }
}

// ---------------- rpy heads: 7 -> 256 -> 256 -> 2 ----------------
// 16 samples/block (M=128 rows), 256 threads. Wave w: rta=(w&1)*4 (4 row-tiles), nh=w>>1.
__global__ __launch_bounds__(256, 2)
void rpy_mfma(const float* __restrict__ x,
              const float* __restrict__ rW0, const float* __restrict__ rb0,
              const float* __restrict__ rb1,
              const float* __restrict__ rW2, const float* __restrict__ rb2,
              const float* __restrict__ pW0, const float* __restrict__ pb0,
              const float* __restrict__ pb1,
              const float* __restrict__ pW2, const float* __restrict__ pb2,
              const float* __restrict__ yW0, const float* __restrict__ yb0,
              const float* __restrict__ yb1,
              const float* __restrict__ yW2, const float* __restrict__ yb2,
              const unsigned short* __restrict__ wsBase,
              float* __restrict__ out, int ns)
{
    extern __shared__ unsigned short sA[];      // 32768 shorts = 64 KB (128 rows x 256 k)
    __shared__ float sB0[256];
    __shared__ float sB1[256];
    __shared__ float sW2[512];
    __shared__ float sQ[16][8];
    __shared__ float sQd[16][8];
    __shared__ float sAcc[2][128][2];
    __shared__ float sSum[128][2];

    const int tid = threadIdx.x;
    const int m0  = blockIdx.x * 16;
    const int h   = blockIdx.y;

    const float* W0 = (h == 0) ? rW0 : (h == 1) ? pW0 : yW0;
    const float* b0 = (h == 0) ? rb0 : (h == 1) ? pb0 : yb0;
    const float* b1 = (h == 0) ? rb1 : (h == 1) ? pb1 : yb1;
    const float* W2 = (h == 0) ? rW2 : (h == 1) ? pW2 : yW2;
    const float* b2 = (h == 0) ? rb2 : (h == 1) ? pb2 : yb2;
    const unsigned short* wsW1 = wsBase + 262144 + h * 65536;

    if (tid < 256) { sB0[tid] = b0[tid]; sB1[tid] = b1[tid]; }
    for (int i = tid; i < 512; i += 256) sW2[i] = W2[i];
    if (tid < 224) {
        int m = tid / 14, c = tid % 14;
        float v = x[(m0 + m) * 14 + c];
        if (c < 7) sQ[m][c] = v; else sQd[m][c - 7] = v;
    }
    __syncthreads();

    const float4* W04 = (const float4*)W0;
    #pragma unroll
    for (int t = 0; t < 2; ++t) {
        int item = tid + t * 256;            // 512 items: (s in 0..15, k8 in 0..31)
        int s = item >> 5, k8 = item & 31;
        float q[7], w0v[7][8];
        #pragma unroll
        for (int i = 0; i < 7; i++) {
            q[i] = sQ[s][i];
            float4 a = W04[i * 64 + k8 * 2], b4 = W04[i * 64 + k8 * 2 + 1];
            w0v[i][0]=a.x; w0v[i][1]=a.y; w0v[i][2]=a.z; w0v[i][3]=a.w;
            w0v[i][4]=b4.x; w0v[i][5]=b4.y; w0v[i][6]=b4.z; w0v[i][7]=b4.w;
        }
        float hv[8], dv[8];
        #pragma unroll
        for (int jj = 0; jj < 8; jj++) {
            float z = sB0[k8 * 8 + jj];
            #pragma unroll
            for (int i = 0; i < 7; i++) z = fmaf(q[i], w0v[i][jj], z);
            float hh = sig(z);
            hv[jj] = hh; dv[jj] = hh - hh * hh;
        }
        int kt = k8 >> 2, kq = k8 & 3;
        int rr0 = s * 8;
        {
            short8 v;
            #pragma unroll
            for (int jj = 0; jj < 8; jj++) v[jj] = (short)f2bf(hv[jj]);
            *(short8*)&sA[((rr0 >> 4) * 8 + kt) * 512 + (kq * 16 + (rr0 & 15)) * 8] = v;
        }
        #pragma unroll
        for (int i = 0; i < 7; i++) {
            int rr = rr0 + 1 + i;
            short8 v;
            #pragma unroll
            for (int jj = 0; jj < 8; jj++) v[jj] = (short)f2bf(dv[jj] * w0v[i][jj]);
            *(short8*)&sA[((rr >> 4) * 8 + kt) * 512 + (kq * 16 + (rr & 15)) * 8] = v;
        }
    }
    __syncthreads();

    const int w = tid >> 6, lane = tid & 63;
    const int rta = (w & 1) * 4, nh = w >> 1;
    const int quad = lane >> 4, col = lane & 15;
    const int srcl = lane & 47;

    short8 afr[4][8];
    #pragma unroll
    for (int rt2 = 0; rt2 < 4; ++rt2)
        #pragma unroll
        for (int kt = 0; kt < 8; ++kt)
            afr[rt2][kt] = *(const short8*)&sA[((rta + rt2) * 8 + kt) * 512 + lane * 8];

    float ep[4][4][2];
    #pragma unroll
    for (int a = 0; a < 4; a++) for (int b = 0; b < 4; b++) for (int c = 0; c < 2; c++) ep[a][b][c] = 0.f;
    const floatx4 z4 = {0.f, 0.f, 0.f, 0.f};

    for (int ct = 0; ct < 8; ++ct) {
        floatx4 acc[4] = {z4, z4, z4, z4};
        const short8* bp = (const short8*)wsW1 + (size_t)((nh * 8 + ct) * 8) * 64 + lane;
        #pragma unroll
        for (int kt = 0; kt < 8; ++kt) {
            short8 bf = bp[kt * 64];
            #pragma unroll
            for (int rt2 = 0; rt2 < 4; ++rt2)
                acc[rt2] = __builtin_amdgcn_mfma_f32_16x16x32_bf16(afr[rt2][kt], bf, acc[rt2], 0, 0, 0);
        }
        const int n = nh * 128 + ct * 16 + col;
        const float b1n = sB1[n];
        const float w20 = sW2[n * 2], w21 = sW2[n * 2 + 1];
        #pragma unroll
        for (int rt2 = 0; rt2 < 4; ++rt2) {
            float z2c = __shfl(acc[rt2][0], srcl);
            float h2 = sig(z2c + b1n);
            float d2 = h2 - h2 * h2;
            #pragma unroll
            for (int r = 0; r < 4; ++r) {
                float g = ((quad & 1) == 0 && r == 0) ? h2 : d2 * acc[rt2][r];
                ep[rt2][r][0] = fmaf(g, w20, ep[rt2][r][0]);
                ep[rt2][r][1] = fmaf(g, w21, ep[rt2][r][1]);
            }
        }
    }

    #pragma unroll
    for (int mask = 1; mask <= 8; mask <<= 1)
        #pragma unroll
        for (int a = 0; a < 4; a++)
            #pragma unroll
            for (int b = 0; b < 4; b++)
                #pragma unroll
                for (int c = 0; c < 2; c++)
                    ep[a][b][c] += __shfl_xor(ep[a][b][c], mask);
    if (col == 0) {
        #pragma unroll
        for (int rt2 = 0; rt2 < 4; ++rt2)
            #pragma unroll
            for (int r = 0; r < 4; ++r) {
                int row = (rta + rt2) * 16 + quad * 4 + r;
                sAcc[nh][row][0] = ep[rt2][r][0];
                sAcc[nh][row][1] = ep[rt2][r][1];
            }
    }
    __syncthreads();

    if (tid < 256) {
        int row = tid >> 1, j = tid & 1;
        float v = sAcc[0][row][j] + sAcc[1][row][j];
        if ((row & 7) == 0) v += b2[j];
        sSum[row][j] = v;
    }
    __syncthreads();

    const long JTOT = (long)ns * 18, OUTA = (long)ns * 81, JANG = (long)ns * 87;
    if (tid < 16) {
        int s = tid;
        long M = m0 + s;
        float y0 = sSum[s * 8][0], y1 = sSum[s * 8][1];
        float sv = sinf(y0), cv = cosf(y1);
        out[M * 18 + 3 + h] = sv;
        out[M * 18 + 6 + h] = cv;
        out[OUTA + M * 6 + 3 + h] = atan2f(sv, cv);
        float f0 = cosf(y0), f1 = -sinf(y1);
        float inv = 1.0f / fmaf(sv, sv, cv * cv);
        float v0 = 0.f, v1 = 0.f;
        #pragma unroll
        for (int i = 0; i < 7; i++) {
            float r0 = f0 * sSum[s * 8 + 1 + i][0];
            float r1 = f1 * sSum[s * 8 + 1 + i][1];
            out[JTOT + M * 63 + (3 + h) * 7 + i] = r0;
            out[JTOT + M * 63 + (6 + h) * 7 + i] = r1;
            out[JANG + M * 42 + (3 + h) * 7 + i] = (cv * r0 - sv * r1) * inv;
            v0 = fmaf(r0, sQd[s][i], v0);
            v1 = fmaf(r1, sQd[s][i], v1);
        }
        out[M * 18 + 12 + h] = v0;
        out[M * 18 + 15 + h] = v1;
    }
}

extern "C" void kernel_launch(void* const* d_in, const int* in_sizes, int n_in,
                              void* d_out, int out_size, void* d_ws, size_t ws_size,
                              hipStream_t stream) {
    (void)n_in; (void)out_size; (void)ws_size;
    const float* x = (const float*)d_in[0];
    float* out = (float*)d_out;
    unsigned short* ws = (unsigned short*)d_ws;
    const int ns = in_sizes[0] / 14;

    convert_w1<<<dim3((512 * 512) / 256), 256, 0, stream>>>((const float*)d_in[3],  ws,          512, 9);
    convert_w1<<<dim3((256 * 256) / 256), 256, 0, stream>>>((const float*)d_in[9],  ws + 262144, 256, 8);
    convert_w1<<<dim3((256 * 256) / 256), 256, 0, stream>>>((const float*)d_in[15], ws + 327680, 256, 8);
    convert_w1<<<dim3((256 * 256) / 256), 256, 0, stream>>>((const float*)d_in[21], ws + 393216, 256, 8);

    pos_mfma<<<dim3(ns / 8), 256, 65536, stream>>>(
        x,
        (const float*)d_in[1], (const float*)d_in[2],
        (const float*)d_in[4],
        (const float*)d_in[5], (const float*)d_in[6],
        ws, out, ns);

    rpy_mfma<<<dim3(ns / 16, 3), 256, 65536, stream>>>(
        x,
        (const float*)d_in[7],  (const float*)d_in[8],  (const float*)d_in[10],
        (const float*)d_in[11], (const float*)d_in[12],
        (const float*)d_in[13], (const float*)d_in[14], (const float*)d_in[16],
        (const float*)d_in[17], (const float*)d_in[18],
        (const float*)d_in[19], (const float*)d_in[20], (const float*)d_in[22],
        (const float*)d_in[23], (const float*)d_in[24],
        ws, out, ns);
}

// Round 4
// 339.532 us; speedup vs baseline: 6.8542x; 1.0934x over previous
//
#include <hip/hip_runtime.h>
#include <math.h>

typedef __attribute__((ext_vector_type(8))) short short8;
typedef __attribute__((ext_vector_type(4))) float floatx4;

__device__ __forceinline__ float sig(float z) { return 1.0f / (1.0f + __expf(-z)); }

__device__ __forceinline__ unsigned short f2bf(float f) {
    unsigned u = __float_as_uint(f);
    u = (u + 0x7FFFu + ((u >> 16) & 1u)) >> 16;   // RNE
    return (unsigned short)u;
}

// Convert H x H fp32 weight (row-major [k][n]) into bf16 pre-swizzled into
// MFMA 16x16x32 B-fragment order: block = (n>>4)*(H/32) + (k>>5),
// lane = ((k>>3)&3)*16 + (n&15), j = k&7; dst[(block*64+lane)*8 + j].
__global__ void convert_w1(const float* __restrict__ src, unsigned short* __restrict__ dst,
                           int H, int logH) {
    int idx = blockIdx.x * 256 + threadIdx.x;
    if (idx >= H * H) return;
    int n = idx & (H - 1), k = idx >> logH;
    int KT = H >> 5;
    int blk = (n >> 4) * KT + (k >> 5);
    int lane = ((k >> 3) & 3) * 16 + (n & 15);
    int j = k & 7;
    dst[(blk * 64 + lane) * 8 + j] = f2bf(src[idx]);
}

// ---------------- pos net: 7 -> 512 -> 512 -> 3 ----------------
// 8 samples/block (M=64 rows), 256 threads. Wave w: rta=(w&1)*2, nh=w>>1.
// kt OUTER / ct INNER: acc[2][16] persistent in regs; A-frags re-read per kt only.
__global__ __launch_bounds__(256, 2)
void pos_mfma(const float* __restrict__ x,
              const float* __restrict__ W0, const float* __restrict__ b0,
              const float* __restrict__ b1,
              const float* __restrict__ W2, const float* __restrict__ b2,
              const unsigned short* __restrict__ wsW1,
              float* __restrict__ out, int ns)
{
    extern __shared__ unsigned short sA[];      // 32768 shorts = 64 KB
    __shared__ float sB0[512];
    __shared__ float sB1[512];
    __shared__ float sW2[1536];
    __shared__ float sQ[8][8];
    __shared__ float sQd[8][8];
    __shared__ float sAcc[2][64][3];
    __shared__ float sSum[64][3];

    const int tid = threadIdx.x;
    const int m0  = blockIdx.x * 8;

    for (int i = tid; i < 512;  i += 256) { sB0[i] = b0[i]; sB1[i] = b1[i]; }
    for (int i = tid; i < 1536; i += 256) sW2[i] = W2[i];
    if (tid < 112) {
        int m = tid / 14, c = tid % 14;
        float v = x[(m0 + m) * 14 + c];
        if (c < 7) sQ[m][c] = v; else sQd[m][c - 7] = v;
    }
    __syncthreads();

    // Build A (h1 row + 7 tangent rows per sample) in kt-XOR-swizzled fragment order.
    const float4* W04 = (const float4*)W0;
    #pragma unroll
    for (int t = 0; t < 2; ++t) {
        int item = tid + t * 256;            // 512 items: (s, k8)
        int s = item >> 6, k8 = item & 63;   // k8: group of 8 k
        float q[7], w0v[7][8];
        #pragma unroll
        for (int i = 0; i < 7; i++) {
            q[i] = sQ[s][i];
            float4 a = W04[i * 128 + k8 * 2], b4 = W04[i * 128 + k8 * 2 + 1];
            w0v[i][0]=a.x; w0v[i][1]=a.y; w0v[i][2]=a.z; w0v[i][3]=a.w;
            w0v[i][4]=b4.x; w0v[i][5]=b4.y; w0v[i][6]=b4.z; w0v[i][7]=b4.w;
        }
        float hv[8], dv[8];
        #pragma unroll
        for (int jj = 0; jj < 8; jj++) {
            float z = sB0[k8 * 8 + jj];
            #pragma unroll
            for (int i = 0; i < 7; i++) z = fmaf(q[i], w0v[i][jj], z);
            float h = sig(z);
            hv[jj] = h; dv[jj] = h - h * h;
        }
        int kt = k8 >> 2, kq = k8 & 3, sw = kt & 7;
        int rr0 = s * 8;
        {
            short8 v;
            #pragma unroll
            for (int jj = 0; jj < 8; jj++) v[jj] = (short)f2bf(hv[jj]);
            *(short8*)&sA[((rr0 >> 4) * 16 + kt) * 512 + ((kq * 16 + (rr0 & 15)) ^ sw) * 8] = v;
        }
        #pragma unroll
        for (int i = 0; i < 7; i++) {
            int rr = rr0 + 1 + i;
            short8 v;
            #pragma unroll
            for (int jj = 0; jj < 8; jj++) v[jj] = (short)f2bf(dv[jj] * w0v[i][jj]);
            *(short8*)&sA[((rr >> 4) * 16 + kt) * 512 + ((kq * 16 + (rr & 15)) ^ sw) * 8] = v;
        }
    }
    __syncthreads();

    const int w = tid >> 6, lane = tid & 63;
    const int rta = (w & 1) * 2, nh = w >> 1;
    const int quad = lane >> 4, col = lane & 15;
    const int srcl = lane & 47;
    const floatx4 z4 = {0.f, 0.f, 0.f, 0.f};

    floatx4 acc[2][16];
    #pragma unroll
    for (int rt = 0; rt < 2; rt++)
        #pragma unroll
        for (int ct = 0; ct < 16; ct++) acc[rt][ct] = z4;

    for (int kt = 0; kt < 16; ++kt) {
        const int sw = kt & 7;
        short8 bf[16];
        const short8* bp = (const short8*)wsW1 + (size_t)(nh * 16 * 16 + kt) * 64 + lane;
        #pragma unroll
        for (int ct = 0; ct < 16; ++ct) bf[ct] = bp[ct * 16 * 64];
        short8 a0 = *(const short8*)&sA[((rta + 0) * 16 + kt) * 512 + (lane ^ sw) * 8];
        short8 a1 = *(const short8*)&sA[((rta + 1) * 16 + kt) * 512 + (lane ^ sw) * 8];
        #pragma unroll
        for (int ct = 0; ct < 16; ++ct) {
            acc[0][ct] = __builtin_amdgcn_mfma_f32_16x16x32_bf16(a0, bf[ct], acc[0][ct], 0, 0, 0);
            acc[1][ct] = __builtin_amdgcn_mfma_f32_16x16x32_bf16(a1, bf[ct], acc[1][ct], 0, 0, 0);
        }
    }

    // epilogue: layer-2 contraction from acc registers
    float ep[2][4][3];
    #pragma unroll
    for (int a = 0; a < 2; a++) for (int b = 0; b < 4; b++) for (int c = 0; c < 3; c++) ep[a][b][c] = 0.f;

    #pragma unroll
    for (int ct = 0; ct < 16; ++ct) {
        const int n = nh * 256 + ct * 16 + col;
        const float b1n = sB1[n];
        const float w20 = sW2[n * 3], w21 = sW2[n * 3 + 1], w22 = sW2[n * 3 + 2];
        #pragma unroll
        for (int rt2 = 0; rt2 < 2; ++rt2) {
            float z2c = __shfl(acc[rt2][ct][0], srcl);
            float h2 = sig(z2c + b1n);
            float d2 = h2 - h2 * h2;
            #pragma unroll
            for (int r = 0; r < 4; ++r) {
                float g = ((quad & 1) == 0 && r == 0) ? h2 : d2 * acc[rt2][ct][r];
                ep[rt2][r][0] = fmaf(g, w20, ep[rt2][r][0]);
                ep[rt2][r][1] = fmaf(g, w21, ep[rt2][r][1]);
                ep[rt2][r][2] = fmaf(g, w22, ep[rt2][r][2]);
            }
        }
    }

    #pragma unroll
    for (int mask = 1; mask <= 8; mask <<= 1)
        #pragma unroll
        for (int a = 0; a < 2; a++)
            #pragma unroll
            for (int b = 0; b < 4; b++)
                #pragma unroll
                for (int c = 0; c < 3; c++)
                    ep[a][b][c] += __shfl_xor(ep[a][b][c], mask);
    if (col == 0) {
        #pragma unroll
        for (int rt2 = 0; rt2 < 2; ++rt2)
            #pragma unroll
            for (int r = 0; r < 4; ++r) {
                int row = (rta + rt2) * 16 + quad * 4 + r;
                sAcc[nh][row][0] = ep[rt2][r][0];
                sAcc[nh][row][1] = ep[rt2][r][1];
                sAcc[nh][row][2] = ep[rt2][r][2];
            }
    }
    __syncthreads();

    const long JTOT = (long)ns * 18, OUTA = (long)ns * 81, JANG = (long)ns * 87;
    if (tid < 192) {
        int row = tid / 3, j = tid % 3;
        float v = sAcc[0][row][j] + sAcc[1][row][j];
        int s = row >> 3, i = row & 7;
        long M = m0 + s;
        if (i == 0) { v += b2[j]; out[M * 18 + j] = v; out[OUTA + M * 6 + j] = v; }
        else        { out[JTOT + M * 63 + j * 7 + (i - 1)] = v;
                      out[JANG + M * 42 + j * 7 + (i - 1)] = v; }
        sSum[row][j] = v;
    }
    __syncthreads();
    if (tid < 24) {
        int s = tid / 3, j = tid % 3;
        float vel = 0.f;
        #pragma unroll
        for (int i = 0; i < 7; i++) vel = fmaf(sSum[s * 8 + 1 + i][j], sQd[s][i], vel);
        out[(long)(m0 + s) * 18 + 9 + j] = vel;
    }
}

// ---------------- rpy heads: 7 -> 256 -> 256 -> 2 ----------------
// 16 samples/block (M=128 rows), 256 threads. kt outer / ct inner; acc[4][8] in regs.
__global__ __launch_bounds__(256, 2)
void rpy_mfma(const float* __restrict__ x,
              const float* __restrict__ rW0, const float* __restrict__ rb0,
              const float* __restrict__ rb1,
              const float* __restrict__ rW2, const float* __restrict__ rb2,
              const float* __restrict__ pW0, const float* __restrict__ pb0,
              const float* __restrict__ pb1,
              const float* __restrict__ pW2, const float* __restrict__ pb2,
              const float* __restrict__ yW0, const float* __restrict__ yb0,
              const float* __restrict__ yb1,
              const float* __restrict__ yW2, const float* __restrict__ yb2,
              const unsigned short* __restrict__ wsBase,
              float* __restrict__ out, int ns)
{
    extern __shared__ unsigned short sA[];      // 64 KB (128 rows x 256 k)
    __shared__ float sB0[256];
    __shared__ float sB1[256];
    __shared__ float sW2[512];
    __shared__ float sQ[16][8];
    __shared__ float sQd[16][8];
    __shared__ float sAcc[2][128][2];
    __shared__ float sSum[128][2];

    const int tid = threadIdx.x;
    const int m0  = blockIdx.x * 16;
    const int h   = blockIdx.y;

    const float* W0 = (h == 0) ? rW0 : (h == 1) ? pW0 : yW0;
    const float* b0 = (h == 0) ? rb0 : (h == 1) ? pb0 : yb0;
    const float* b1 = (h == 0) ? rb1 : (h == 1) ? pb1 : yb1;
    const float* W2 = (h == 0) ? rW2 : (h == 1) ? pW2 : yW2;
    const float* b2 = (h == 0) ? rb2 : (h == 1) ? pb2 : yb2;
    const unsigned short* wsW1 = wsBase + 262144 + h * 65536;

    if (tid < 256) { sB0[tid] = b0[tid]; sB1[tid] = b1[tid]; }
    for (int i = tid; i < 512; i += 256) sW2[i] = W2[i];
    if (tid < 224) {
        int m = tid / 14, c = tid % 14;
        float v = x[(m0 + m) * 14 + c];
        if (c < 7) sQ[m][c] = v; else sQd[m][c - 7] = v;
    }
    __syncthreads();

    const float4* W04 = (const float4*)W0;
    #pragma unroll
    for (int t = 0; t < 2; ++t) {
        int item = tid + t * 256;            // 512 items: (s in 0..15, k8 in 0..31)
        int s = item >> 5, k8 = item & 31;
        float q[7], w0v[7][8];
        #pragma unroll
        for (int i = 0; i < 7; i++) {
            q[i] = sQ[s][i];
            float4 a = W04[i * 64 + k8 * 2], b4 = W04[i * 64 + k8 * 2 + 1];
            w0v[i][0]=a.x; w0v[i][1]=a.y; w0v[i][2]=a.z; w0v[i][3]=a.w;
            w0v[i][4]=b4.x; w0v[i][5]=b4.y; w0v[i][6]=b4.z; w0v[i][7]=b4.w;
        }
        float hv[8], dv[8];
        #pragma unroll
        for (int jj = 0; jj < 8; jj++) {
            float z = sB0[k8 * 8 + jj];
            #pragma unroll
            for (int i = 0; i < 7; i++) z = fmaf(q[i], w0v[i][jj], z);
            float hh = sig(z);
            hv[jj] = hh; dv[jj] = hh - hh * hh;
        }
        int kt = k8 >> 2, kq = k8 & 3, sw = kt & 7;
        int rr0 = s * 8;
        {
            short8 v;
            #pragma unroll
            for (int jj = 0; jj < 8; jj++) v[jj] = (short)f2bf(hv[jj]);
            *(short8*)&sA[((rr0 >> 4) * 8 + kt) * 512 + ((kq * 16 + (rr0 & 15)) ^ sw) * 8] = v;
        }
        #pragma unroll
        for (int i = 0; i < 7; i++) {
            int rr = rr0 + 1 + i;
            short8 v;
            #pragma unroll
            for (int jj = 0; jj < 8; jj++) v[jj] = (short)f2bf(dv[jj] * w0v[i][jj]);
            *(short8*)&sA[((rr >> 4) * 8 + kt) * 512 + ((kq * 16 + (rr & 15)) ^ sw) * 8] = v;
        }
    }
    __syncthreads();

    const int w = tid >> 6, lane = tid & 63;
    const int rta = (w & 1) * 4, nh = w >> 1;
    const int quad = lane >> 4, col = lane & 15;
    const int srcl = lane & 47;
    const floatx4 z4 = {0.f, 0.f, 0.f, 0.f};

    floatx4 acc[4][8];
    #pragma unroll
    for (int rt = 0; rt < 4; rt++)
        #pragma unroll
        for (int ct = 0; ct < 8; ct++) acc[rt][ct] = z4;

    for (int kt = 0; kt < 8; ++kt) {
        const int sw = kt & 7;
        short8 bf[8];
        const short8* bp = (const short8*)wsW1 + (size_t)(nh * 8 * 8 + kt) * 64 + lane;
        #pragma unroll
        for (int ct = 0; ct < 8; ++ct) bf[ct] = bp[ct * 8 * 64];
        short8 a[4];
        #pragma unroll
        for (int rt = 0; rt < 4; ++rt)
            a[rt] = *(const short8*)&sA[((rta + rt) * 8 + kt) * 512 + (lane ^ sw) * 8];
        #pragma unroll
        for (int ct = 0; ct < 8; ++ct)
            #pragma unroll
            for (int rt = 0; rt < 4; ++rt)
                acc[rt][ct] = __builtin_amdgcn_mfma_f32_16x16x32_bf16(a[rt], bf[ct], acc[rt][ct], 0, 0, 0);
    }

    float ep[4][4][2];
    #pragma unroll
    for (int a = 0; a < 4; a++) for (int b = 0; b < 4; b++) for (int c = 0; c < 2; c++) ep[a][b][c] = 0.f;

    #pragma unroll
    for (int ct = 0; ct < 8; ++ct) {
        const int n = nh * 128 + ct * 16 + col;
        const float b1n = sB1[n];
        const float w20 = sW2[n * 2], w21 = sW2[n * 2 + 1];
        #pragma unroll
        for (int rt2 = 0; rt2 < 4; ++rt2) {
            float z2c = __shfl(acc[rt2][ct][0], srcl);
            float h2 = sig(z2c + b1n);
            float d2 = h2 - h2 * h2;
            #pragma unroll
            for (int r = 0; r < 4; ++r) {
                float g = ((quad & 1) == 0 && r == 0) ? h2 : d2 * acc[rt2][ct][r];
                ep[rt2][r][0] = fmaf(g, w20, ep[rt2][r][0]);
                ep[rt2][r][1] = fmaf(g, w21, ep[rt2][r][1]);
            }
        }
    }

    #pragma unroll
    for (int mask = 1; mask <= 8; mask <<= 1)
        #pragma unroll
        for (int a = 0; a < 4; a++)
            #pragma unroll
            for (int b = 0; b < 4; b++)
                #pragma unroll
                for (int c = 0; c < 2; c++)
                    ep[a][b][c] += __shfl_xor(ep[a][b][c], mask);
    if (col == 0) {
        #pragma unroll
        for (int rt2 = 0; rt2 < 4; ++rt2)
            #pragma unroll
            for (int r = 0; r < 4; ++r) {
                int row = (rta + rt2) * 16 + quad * 4 + r;
                sAcc[nh][row][0] = ep[rt2][r][0];
                sAcc[nh][row][1] = ep[rt2][r][1];
            }
    }
    __syncthreads();

    if (tid < 256) {
        int row = tid >> 1, j = tid & 1;
        float v = sAcc[0][row][j] + sAcc[1][row][j];
        if ((row & 7) == 0) v += b2[j];
        sSum[row][j] = v;
    }
    __syncthreads();

    const long JTOT = (long)ns * 18, OUTA = (long)ns * 81, JANG = (long)ns * 87;
    if (tid < 16) {
        int s = tid;
        long M = m0 + s;
        float y0 = sSum[s * 8][0], y1 = sSum[s * 8][1];
        float sv = sinf(y0), cv = cosf(y1);
        out[M * 18 + 3 + h] = sv;
        out[M * 18 + 6 + h] = cv;
        out[OUTA + M * 6 + 3 + h] = atan2f(sv, cv);
        float f0 = cosf(y0), f1 = -sinf(y1);
        float inv = 1.0f / fmaf(sv, sv, cv * cv);
        float v0 = 0.f, v1 = 0.f;
        #pragma unroll
        for (int i = 0; i < 7; i++) {
            float r0 = f0 * sSum[s * 8 + 1 + i][0];
            float r1 = f1 * sSum[s * 8 + 1 + i][1];
            out[JTOT + M * 63 + (3 + h) * 7 + i] = r0;
            out[JTOT + M * 63 + (6 + h) * 7 + i] = r1;
            out[JANG + M * 42 + (3 + h) * 7 + i] = (cv * r0 - sv * r1) * inv;
            v0 = fmaf(r0, sQd[s][i], v0);
            v1 = fmaf(r1, sQd[s][i], v1);
        }
        out[M * 18 + 12 + h] = v0;
        out[M * 18 + 15 + h] = v1;
    }
}

extern "C" void kernel_launch(void* const* d_in, const int* in_sizes, int n_in,
                              void* d_out, int out_size, void* d_ws, size_t ws_size,
                              hipStream_t stream) {
    (void)n_in; (void)out_size; (void)ws_size;
    const float* x = (const float*)d_in[0];
    float* out = (float*)d_out;
    unsigned short* ws = (unsigned short*)d_ws;
    const int ns = in_sizes[0] / 14;

    convert_w1<<<dim3((512 * 512) / 256), 256, 0, stream>>>((const float*)d_in[3],  ws,          512, 9);
    convert_w1<<<dim3((256 * 256) / 256), 256, 0, stream>>>((const float*)d_in[9],  ws + 262144, 256, 8);
    convert_w1<<<dim3((256 * 256) / 256), 256, 0, stream>>>((const float*)d_in[15], ws + 327680, 256, 8);
    convert_w1<<<dim3((256 * 256) / 256), 256, 0, stream>>>((const float*)d_in[21], ws + 393216, 256, 8);

    pos_mfma<<<dim3(ns / 8), 256, 65536, stream>>>(
        x,
        (const float*)d_in[1], (const float*)d_in[2],
        (const float*)d_in[4],
        (const float*)d_in[5], (const float*)d_in[6],
        ws, out, ns);

    rpy_mfma<<<dim3(ns / 16, 3), 256, 65536, stream>>>(
        x,
        (const float*)d_in[7],  (const float*)d_in[8],  (const float*)d_in[10],
        (const float*)d_in[11], (const float*)d_in[12],
        (const float*)d_in[13], (const float*)d_in[14], (const float*)d_in[16],
        (const float*)d_in[17], (const float*)d_in[18],
        (const float*)d_in[19], (const float*)d_in[20], (const float*)d_in[22],
        (const float*)d_in[23], (const float*)d_in[24],
        ws, out, ns);
}